// Round 2
// baseline (262.346 us; speedup 1.0000x reference)
//
#include <hip/hip_runtime.h>
#include <math.h>

#define L 2048
#define NB 16
#define ROWS_PER_BLOCK 16
#define THREADS 256
#define GAF_EPS 1e-8f

// native clang vector type: __builtin_nontemporal_store requires this
// (HIP's float4 is a struct and is rejected by the builtin).
typedef float f32x4 __attribute__((ext_vector_type(4)));

// gaf[b,i,j] = cos(phi_i + phi_j) = c_i*c_j - s_i*s_j
// with c = clip(2*(x-min)/(max-min+eps) - 1), s = sqrt(1 - c^2).
//
// Write-streaming bound: 256 MiB of output. The harness's own fillBuffer
// hits 6.6 TB/s (162 us for 1 GiB) => ~41 us floor for this kernel.
// v2 changes vs v1 (92 us):
//   - nontemporal (nt) stores: no L2/L3 allocate for the write-once stream
//   - loop interchange: cj/sj float4 loaded ONCE per column chunk (was per row),
//     ci/si hoisted to registers => stream loop is stores + FMAs only
__global__ __launch_bounds__(THREADS) void gaf_kernel(const float* __restrict__ x,
                                                      float* __restrict__ out) {
    __shared__ float sc[L];   // c_j per column of this batch
    __shared__ float ss[L];   // s_j per column
    __shared__ float red[8];  // 4 waves: min in [0..3], max in [4..7]

    const int chunks_per_batch = L / ROWS_PER_BLOCK;           // 128
    const int b = blockIdx.x / chunks_per_batch;
    const int i0 = (blockIdx.x % chunks_per_batch) * ROWS_PER_BLOCK;
    const int t = threadIdx.x;
    const float* __restrict__ xrow = x + (size_t)b * L;

    // --- load 8 elements/thread (coalesced, stride THREADS), track min/max ---
    float v[8];
    float mn = INFINITY, mx = -INFINITY;
#pragma unroll
    for (int k = 0; k < 8; ++k) {
        v[k] = xrow[t + k * THREADS];
        mn = fminf(mn, v[k]);
        mx = fmaxf(mx, v[k]);
    }
    // wave-level xor butterfly (all 64 lanes end with the result)
#pragma unroll
    for (int off = 32; off > 0; off >>= 1) {
        mn = fminf(mn, __shfl_xor(mn, off));
        mx = fmaxf(mx, __shfl_xor(mx, off));
    }
    const int wave = t >> 6;
    if ((t & 63) == 0) { red[wave] = mn; red[4 + wave] = mx; }
    __syncthreads();
    // every thread folds the 4 wave results locally (no serial t==0 step)
    mn = fminf(fminf(red[0], red[1]), fminf(red[2], red[3]));
    mx = fmaxf(fmaxf(red[4], red[5]), fmaxf(red[6], red[7]));
    const float inv = 1.0f / (mx - mn + GAF_EPS);

    // --- compute c, s into LDS ---
#pragma unroll
    for (int k = 0; k < 8; ++k) {
        float c = 2.0f * ((v[k] - mn) * inv) - 1.0f;
        c = fminf(fmaxf(c, -1.0f + GAF_EPS), 1.0f - GAF_EPS);
        const int idx = t + k * THREADS;
        sc[idx] = c;
        ss[idx] = sqrtf(fmaxf(1.0f - c * c, 0.0f));
    }
    __syncthreads();

    // --- hoist this block's 16 row coefficients into registers (LDS broadcast) ---
    float ci[ROWS_PER_BLOCK], si[ROWS_PER_BLOCK];
#pragma unroll
    for (int i = 0; i < ROWS_PER_BLOCK; ++i) {
        ci[i] = sc[i0 + i];
        si[i] = ss[i0 + i];
    }

    // --- stream 16 output rows; column chunk loaded once, 16 nt-stores back-to-back ---
    float* __restrict__ obase = out + ((size_t)b * L + (size_t)i0) * L;
#pragma unroll
    for (int it = 0; it < L / (4 * THREADS); ++it) {  // 2 iterations
        const int j4 = t + it * THREADS;
        const f32x4 cj = ((const f32x4*)sc)[j4];
        const f32x4 sj = ((const f32x4*)ss)[j4];
#pragma unroll
        for (int i = 0; i < ROWS_PER_BLOCK; ++i) {
            f32x4 o;
            o.x = ci[i] * cj.x - si[i] * sj.x;
            o.y = ci[i] * cj.y - si[i] * sj.y;
            o.z = ci[i] * cj.z - si[i] * sj.z;
            o.w = ci[i] * cj.w - si[i] * sj.w;
            __builtin_nontemporal_store(o, (f32x4*)(obase + (size_t)i * L) + j4);
        }
    }
}

extern "C" void kernel_launch(void* const* d_in, const int* in_sizes, int n_in,
                              void* d_out, int out_size, void* d_ws, size_t ws_size,
                              hipStream_t stream) {
    const float* x = (const float*)d_in[0];
    float* out = (float*)d_out;
    const dim3 grid(NB * (L / ROWS_PER_BLOCK));  // 16 * 128 = 2048 blocks
    gaf_kernel<<<grid, THREADS, 0, stream>>>(x, out);
}

// Round 4
// 260.644 us; speedup vs baseline: 1.0065x; 1.0065x over previous
//
#include <hip/hip_runtime.h>
#include <math.h>

#define L 2048
#define NB 16
#define THREADS 512
#define BLOCKS_PER_BATCH 16                       // 16 batches * 16 = 256 blocks = 1/CU
#define ROWS_PER_BLOCK (L / BLOCKS_PER_BATCH)     // 128 consecutive rows = 1 MiB contiguous
#define GAF_EPS 1e-8f

// native clang vector type: __builtin_nontemporal_store requires this
typedef float f32x4 __attribute__((ext_vector_type(4)));

// gaf[b,i,j] = cos(phi_i + phi_j) = c_i*c_j - s_i*s_j
// with c = clip(2*(x-min)/(max-min+eps) - 1), s = sqrt(1 - c^2).
//
// v3 theory: the harness fill proves 6.3 TB/s write streaming (grid-stride =
// compact sliding window, long sequential DRAM runs). v1/v2 both sat at
// 2.9 TB/s with 2048 resident blocks writing 1KB bursts at 8KB stride =
// DRAM row thrash. v3 mimics the fill: 256 blocks (1/CU), each sweeping
// 1 MiB of CONTIGUOUS output sequentially (8KB per row-step), ~4 sequential
// streams per HBM channel.
__global__ __launch_bounds__(THREADS) void gaf_kernel(const float* __restrict__ x,
                                                      float* __restrict__ out) {
    __shared__ float sc[L];    // c_i per row of this batch
    __shared__ float ss[L];    // s_i per row
    __shared__ float red[16];  // 8 waves: min in [0..7], max in [8..15]

    const int b = blockIdx.x / BLOCKS_PER_BATCH;
    const int q = blockIdx.x % BLOCKS_PER_BATCH;
    const int t = threadIdx.x;

    // --- load 4 elements/thread as one float4 (whole batch row, coalesced) ---
    const f32x4 v = ((const f32x4*)(x + (size_t)b * L))[t];
    float mn = fminf(fminf(v.x, v.y), fminf(v.z, v.w));
    float mx = fmaxf(fmaxf(v.x, v.y), fmaxf(v.z, v.w));

    // wave-level xor butterfly (all 64 lanes end with the result)
#pragma unroll
    for (int off = 32; off > 0; off >>= 1) {
        mn = fminf(mn, __shfl_xor(mn, off));
        mx = fmaxf(mx, __shfl_xor(mx, off));
    }
    const int wave = t >> 6;
    if ((t & 63) == 0) { red[wave] = mn; red[8 + wave] = mx; }
    __syncthreads();
    mn = red[0];
    mx = red[8];
#pragma unroll
    for (int w = 1; w < 8; ++w) {
        mn = fminf(mn, red[w]);
        mx = fmaxf(mx, red[8 + w]);
    }
    const float inv = 1.0f / (mx - mn + GAF_EPS);

    // --- c,s for this thread's 4 columns: keep in REGISTERS (these are the
    //     cj/sj this thread needs for every row), and publish to LDS for the
    //     per-row broadcast reads ---
    f32x4 c4, s4;
    {
        float cv[4] = {v.x, v.y, v.z, v.w};
#pragma unroll
        for (int k = 0; k < 4; ++k) {
            float c = 2.0f * ((cv[k] - mn) * inv) - 1.0f;
            c = fminf(fmaxf(c, -1.0f + GAF_EPS), 1.0f - GAF_EPS);
            cv[k] = c;
        }
        c4.x = cv[0]; c4.y = cv[1]; c4.z = cv[2]; c4.w = cv[3];
        s4.x = sqrtf(fmaxf(1.0f - c4.x * c4.x, 0.0f));
        s4.y = sqrtf(fmaxf(1.0f - c4.y * c4.y, 0.0f));
        s4.z = sqrtf(fmaxf(1.0f - c4.z * c4.z, 0.0f));
        s4.w = sqrtf(fmaxf(1.0f - c4.w * c4.w, 0.0f));
    }
    ((f32x4*)sc)[t] = c4;
    ((f32x4*)ss)[t] = s4;
    __syncthreads();

    // --- sweep 128 CONSECUTIVE rows (1 MiB contiguous, strictly sequential).
    //     Per row: 2 broadcast LDS reads + 8 VALU + 1 nt dwordx4 store. ---
    float* __restrict__ obase =
        out + ((size_t)b * L + (size_t)q * ROWS_PER_BLOCK) * L;
#pragma unroll 8
    for (int m = 0; m < ROWS_PER_BLOCK; ++m) {
        const int r = q * ROWS_PER_BLOCK + m;
        const float ci = sc[r];   // same-address broadcast: conflict-free
        const float si = ss[r];
        f32x4 o;
        o.x = ci * c4.x - si * s4.x;
        o.y = ci * c4.y - si * s4.y;
        o.z = ci * c4.z - si * s4.z;
        o.w = ci * c4.w - si * s4.w;
        __builtin_nontemporal_store(o, (f32x4*)(obase + (size_t)m * L) + t);
    }
}

extern "C" void kernel_launch(void* const* d_in, const int* in_sizes, int n_in,
                              void* d_out, int out_size, void* d_ws, size_t ws_size,
                              hipStream_t stream) {
    const float* x = (const float*)d_in[0];
    float* out = (float*)d_out;
    const dim3 grid(NB * BLOCKS_PER_BATCH);  // 256 blocks, one per CU
    gaf_kernel<<<grid, THREADS, 0, stream>>>(x, out);
}